// Round 12
// baseline (495.976 us; speedup 1.0000x reference)
//
#include <hip/hip_runtime.h>

#define S_LEN   2048
#define HID     4096
#define NHEADS  32
#define NKVH    8
#define HDIM    128
#define NQKV    6144          // NKV*(QPK+2)*HD = 8*6*128
#define ATT_SCALE (1.0f/128.0f)

typedef unsigned short u16;
typedef __attribute__((ext_vector_type(8))) __bf16 bf16x8;
typedef __attribute__((ext_vector_type(4))) float  f32x4;

__device__ __forceinline__ u16 f2bf(float f) {
    union { float f; unsigned u; } x; x.f = f;
    unsigned u = x.u;
    u += 0x7fffu + ((u >> 16) & 1u);   // round-to-nearest-even
    return (u16)(u >> 16);
}
__device__ __forceinline__ float bf2f(u16 v) {
    union { unsigned u; float f; } x; x.u = ((unsigned)v) << 16; return x.f;
}

// ---------------- fp32 -> bf16 conversion ----------------
__global__ __launch_bounds__(256) void cvt_bf16_kernel(const float* __restrict__ in,
                                                       u16* __restrict__ out, int n4) {
    int stride = gridDim.x * blockDim.x;
    for (int i = blockIdx.x * blockDim.x + threadIdx.x; i < n4; i += stride) {
        float4 v = *(const float4*)(in + (size_t)i * 4);
        ushort4 o = make_ushort4(f2bf(v.x), f2bf(v.y), f2bf(v.z), f2bf(v.w));
        *(ushort4*)(out + (size_t)i * 4) = o;
    }
}

// ---------------- full-coverage GEMM: 128 x BN tile, two-gate interleaved schedule ----------------
// EXACT round-8 schedule (best measured: QKV 101-103 us, MfmaUtil ~44).
//   entering tile t: 2+2LB outstanding {A(t),B0(t),B1(t)}
//   P0: +A(t+1); vmcnt(2+LB) forces A(t)+B0(t); barrier; READ_A; MFMA_B(0).
//   P1: +B0(t+1); vmcnt(2+LB) forces B1(t); barrier; MFMA_B(1); +B1(t+1).
//   end: lgkmcnt(0); barrier.
// Never vmcnt(0) in-loop (T4); drain vmcnt(0) after loop (in-flight LDS-DMA
// at s_endpgm corrupts the next WG's LDS — round-2 root cause).
// B-fragments streamed per-n (round-7: in-loop spill corrupts the vmcnt FIFO).
// T2 swizzle (verified 0 conflicts): phys 16B chunk = logical^(row&7),
// both-sides involution: linear gload_lds dest + pre-swizzled source + XOR read.
#define GFENCE() asm volatile("" ::: "memory")
#define GSBAR()  do { GFENCE(); __builtin_amdgcn_s_barrier(); GFENCE(); } while (0)

template <int BN_, int NB_, bool OUT_BF16>
__global__ __launch_bounds__(512, 2) void gemm_fc_kernel(
    const u16* __restrict__ A,   // M x K  bf16
    const u16* __restrict__ B,   // N x K  bf16
    const float* __restrict__ bias,
    void* __restrict__ Cout,     // M x N
    int M, int N, int K)
{
    constexpr int LB = BN_ / 128;          // gload_lds per B-half per wave
    constexpr int VM = 2 + LB;             // counted-wait value (QKV: 5, dense: 4)
    __shared__ u16 lds[16384 + 2 * BN_ * 64];

    const int tid  = threadIdx.x;
    const int wid  = tid >> 6;        // 0..7
    const int lane = tid & 63;
    const int ln   = lane & 15;
    const int quad = lane >> 4;
    const int wr   = wid >> 2;        // 0..1 (M split)
    const int wc   = wid & 3;         // 0..3 (N split)
    const int tileM = blockIdx.y * 128;
    const int tileN = blockIdx.x * BN_;

    f32x4 acc[2][NB_][4];             // [b][n][m]
    #pragma unroll
    for (int b = 0; b < 2; b++)
        #pragma unroll
        for (int n = 0; n < NB_; n++)
            #pragma unroll
            for (int m = 0; m < 4; m++) {
                f32x4 z = {0.f, 0.f, 0.f, 0.f};
                acc[b][n][m] = z;
            }

    const int srho = lane >> 3;                       // row within 8-row group
    const int scol = (((lane & 7) ^ srho) << 3);      // pre-swizzled source chunk

    auto gload = [&](const u16* src, u16* dst) {
        __builtin_amdgcn_global_load_lds(
            (const __attribute__((address_space(1))) void*)src,
            (__attribute__((address_space(3))) void*)dst, 16, 0, 0);
    };
    // A unit: 128 rows, 2 loads/wave
    auto stage_A = [&](int kk, int bb) {
        const int base = bb * 8192;
        #pragma unroll
        for (int s = 0; s < 2; s++) {
            const int rho0 = s * 64 + wid * 8;        // wave-uniform, ≡0 mod 8
            const int rho  = rho0 + srho;
            const u16* src = A + (size_t)(tileM + rho) * K + (size_t)kk * 64 + scol;
            gload(src, &lds[base + rho0 * 64]);
        }
    };
    // B half h: BN/2 rows, LB loads/wave
    auto stage_Bh = [&](int h, int kk, int bb) {
        const int base = 16384 + bb * (BN_ * 64) + h * ((BN_ / 2) * 64);
        #pragma unroll
        for (int s = 0; s < LB; s++) {
            const int rho0 = s * 64 + wid * 8;
            const int rho  = rho0 + srho;
            const u16* src = B + (size_t)(tileN + h * (BN_ / 2) + rho) * K
                               + (size_t)kk * 64 + scol;
            gload(src, &lds[base + rho0 * 64]);
        }
    };

#define WAIT_VM()                                                                   \
    do {                                                                            \
        if constexpr (VM == 5) asm volatile("s_waitcnt vmcnt(5)" ::: "memory");     \
        else                   asm volatile("s_waitcnt vmcnt(4)" ::: "memory");     \
    } while (0)

#define READ_A()                                                                    \
    do {                                                                            \
        _Pragma("unroll")                                                           \
        for (int m = 0; m < 4; m++) {                                               \
            const int ra = wr * 64 + m * 16 + ln;                                   \
            const int ab = buf * 8192 + ra * 64;                                    \
            const int rx = ra & 7;                                                  \
            af[m][0] = *(const bf16x8*)(&lds[ab + ((quad ^ rx) << 3)]);             \
            af[m][1] = *(const bf16x8*)(&lds[ab + (((4 + quad) ^ rx) << 3)]);       \
        }                                                                           \
    } while (0)

// streamed: one bfr pair live at a time (no in-loop spill risk)
#define MFMA_B(b_)                                                                  \
    do {                                                                            \
        __builtin_amdgcn_s_setprio(1);                                              \
        _Pragma("unroll")                                                           \
        for (int n = 0; n < NB_; n++) {                                             \
            const int rb = (b_) * (BN_ / 2) + wc * (NB_ * 16) + n * 16 + ln;        \
            const int bb = 16384 + buf * (BN_ * 64) + rb * 64;                      \
            const int rx = rb & 7;                                                  \
            bf16x8 b0 = *(const bf16x8*)(&lds[bb + ((quad ^ rx) << 3)]);            \
            bf16x8 b1 = *(const bf16x8*)(&lds[bb + (((4 + quad) ^ rx) << 3)]);      \
            _Pragma("unroll")                                                       \
            for (int m = 0; m < 4; m++) {                                           \
                acc[b_][n][m] = __builtin_amdgcn_mfma_f32_16x16x32_bf16(            \
                    af[m][0], b0, acc[b_][n][m], 0, 0, 0);                          \
                acc[b_][n][m] = __builtin_amdgcn_mfma_f32_16x16x32_bf16(            \
                    af[m][1], b1, acc[b_][n][m], 0, 0, 0);                          \
            }                                                                       \
        }                                                                           \
        __builtin_amdgcn_s_setprio(0);                                              \
    } while (0)

    const int nIter = K / 64;

    // prologue: tile 0 -> buf0, order A, B0, B1 (order matters for the ledger)
    stage_A(0, 0); stage_Bh(0, 0, 0); stage_Bh(1, 0, 0);

    bf16x8 af[4][2];

    for (int t = 0; t < nIter; t++) {
        const int buf = t & 1;
        const int bn  = buf ^ 1;
        const int kn  = (t + 1 == nIter) ? 0 : t + 1;   // final-iter dummy keeps counts uniform

        // ---- P0: b=0 needs A(t) + B0(t) ----
        stage_A(kn, bn);
        WAIT_VM();             // forces A(t), B0(t) (this wave)
        GSBAR();               // ... across all waves
        READ_A();
        MFMA_B(0);

        // ---- P1: b=1 needs B1(t); af reused ----
        stage_Bh(0, kn, bn);
        WAIT_VM();             // forces exactly B1(t)
        GSBAR();
        MFMA_B(1);
        stage_Bh(1, kn, bn);

        asm volatile("s_waitcnt lgkmcnt(0)" ::: "memory");  // all buf reads complete
        GSBAR();                                            // before t+1 DMAs into buf
    }

    // CRITICAL drain: final-iter dummy stages still in flight; LDS-DMA landing
    // after s_endpgm faults / corrupts the next workgroup's LDS.
    asm volatile("s_waitcnt vmcnt(0)" ::: "memory");

#undef WAIT_VM
#undef READ_A
#undef MFMA_B

    // epilogue
    #pragma unroll
    for (int b = 0; b < 2; b++)
        #pragma unroll
        for (int n = 0; n < NB_; n++) {
            const int col = tileN + b * (BN_ / 2) + wc * (NB_ * 16) + n * 16 + ln;
            const float bv = bias[col];
            #pragma unroll
            for (int m = 0; m < 4; m++) {
                #pragma unroll
                for (int r = 0; r < 4; r++) {
                    const int row = tileM + wr * 64 + m * 16 + quad * 4 + r;
                    float v = acc[b][n][m][r] + bv;
                    if (OUT_BF16)
                        ((u16*)Cout)[(size_t)row * N + col] = f2bf(v);
                    else
                        ((float*)Cout)[(size_t)row * N + col] = v;
                }
            }
        }
}

// ---------------- RoPE + split qkv (bf16 in, bf16 out) ----------------
__global__ __launch_bounds__(128) void rope_split_kernel(
    const u16* __restrict__ qkv, const int* __restrict__ positions,
    u16* __restrict__ qb_o, u16* __restrict__ kb_o)
{
    const int d   = threadIdx.x;     // 0..127
    const int pos = blockIdx.x;      // 0..S-1
    const int hy  = blockIdx.y;      // 0..39
    const float p = (float)positions[pos];

    const u16* src;
    u16* dst;
    if (hy < NHEADS) {                        // q head
        int kv = hy >> 2, qi = hy & 3;
        src = qkv + (size_t)pos * NQKV + (kv * 6 + qi) * HDIM;
        dst = qb_o + ((size_t)hy * S_LEN + pos) * HDIM;
    } else {                                  // k head
        int kv = hy - NHEADS;
        src = qkv + (size_t)pos * NQKV + (kv * 6 + 4) * HDIM;
        dst = kb_o + ((size_t)kv * S_LEN + pos) * HDIM;
    }
    int d2 = d & 63;
    float inv = expf(-(float)d2 * (13.815510557964274f / 64.0f)); // 1e6^(-d2/64)
    float fr = p * inv;
    float s, c;
    sincosf(fr, &s, &c);
    float x1 = bf2f(src[d2]);
    float x2 = bf2f(src[d2 + 64]);
    float o = (d < 64) ? (x1 * c - x2 * s) : (x2 * c + x1 * s);
    dst[d] = f2bf(o);
}

// ---------------- one-shot V transpose: qkv -> VT (NKV, HD, S) ----------------
__global__ __launch_bounds__(256) void vtrans_kernel(
    const u16* __restrict__ qkv,   // (S, NQKV)
    u16* __restrict__ VT)          // (NKV, HDIM, S)
{
    __shared__ u16 T[64][HDIM + 8];
    const int s0 = blockIdx.x * 64;
    const int kv = blockIdx.y;
    const int tid = threadIdx.x;
    // coalesced read: 64 pos x 128 dim
    #pragma unroll
    for (int p = 0; p < 4; p++) {
        int pos = p * 16 + (tid >> 4);
        int d   = (tid & 15) * 8;
        *(uint4*)&T[pos][d] =
            *(const uint4*)(qkv + (size_t)(s0 + pos) * NQKV + (kv * 6 + 5) * HDIM + d);
    }
    __syncthreads();
    // coalesced write: 128 dim rows x 64 pos
    #pragma unroll
    for (int p = 0; p < 4; p++) {
        int d  = p * 32 + (tid >> 3);
        int sc = (tid & 7) * 8;
        u16 tmp[8];
        #pragma unroll
        for (int j = 0; j < 8; j++) tmp[j] = T[sc + j][d];
        *(uint4*)(VT + ((size_t)kv * HDIM + d) * S_LEN + s0 + sc) = *(uint4*)tmp;
    }
}

// ---------------- blocksparse flash attention, QBLK=128, K/V double-buffered ----------------
// Round-12: counted-vmcnt double-buffer for K/V staging (GEMM-proven pattern).
// Per selected tile: stage(next, buf^1) [4 gload_lds] -> vmcnt(4) [forces
// current tile's 4 units] -> raw barrier -> compute(buf) -> lgkmcnt(0) ->
// barrier [protects buf: NEXT iteration DMAs into buf]. Final tile issues a
// dummy restage (uniform counts); vmcnt(0) drain before epilogue (round-2
// lesson). Selected-tile scan (<=8 steps, vert period 8) is block-uniform ->
// barrier-uniform; 'mine' guard contains no barriers. LDS 2*16K(K) +
// 2*16K(Vt) + 16K(Ps) = 80 KB -> 2 blocks/CU; grid 512 = exactly 2/CU (same
// 16 waves/CU residency as round-11's 48KB/3-block config — dbuf is free).
// Waves 0-3 own 64-row block qbw=2*blk, waves 4-7 own 2*blk+1. V
// pre-transposed (vtrans); 3-bit XOR involution (verified 0 conflicts);
// T13 defer-max; reversed dispatch; setprio on MFMA clusters.
__global__ __launch_bounds__(512, 4) void attn_bs_kernel(
    const u16* __restrict__ Q,   // (NH, S, HD) bf16
    const u16* __restrict__ K,   // (NKV, S, HD)
    const u16* __restrict__ V,   // (NKV, HD, S)  TRANSPOSED
    u16* __restrict__ O)         // (S, NH*HD) bf16
{
    __shared__ u16 Ks[2][64 * 128];   // 2 x 16 KB, swizzled
    __shared__ u16 Vt[2][128 * 64];   // 2 x 16 KB, V^T, swizzled
    __shared__ u16 Ps[8][16 * 64];    // 16 KB, per-wave P, swizzled

    const int blk = (int)gridDim.x - 1 - (int)blockIdx.x;  // heavy blocks first
    const int h   = blockIdx.y;
    const int kv  = h >> 2;
    const int tid  = threadIdx.x;
    const int w    = tid >> 6;        // 0..7
    const int lane = tid & 63;
    const int ln   = lane & 15;
    const int quad = lane >> 4;
    const int qbw  = 2 * blk + (w >> 2);   // this wave's 64-row block index
    const int rb16 = (w & 3) * 16;         // wave's row base within its 64-block

    bf16x8 aq[4];
    {
        const u16* Qg = Q + ((size_t)h * S_LEN + qbw * 64 + rb16 + ln) * HDIM + quad * 8;
        #pragma unroll
        for (int ks = 0; ks < 4; ks++)
            aq[ks] = *(const bf16x8*)(Qg + ks * 32);
    }

    f32x4 oacc[8];
    #pragma unroll
    for (int n = 0; n < 8; n++) { f32x4 z = {0.f,0.f,0.f,0.f}; oacc[n] = z; }
    float mrow[4] = {-1e30f, -1e30f, -1e30f, -1e30f};
    float lrow[4] = {0.f, 0.f, 0.f, 0.f};

    const int kbMax = 2 * blk + 1;

    // stage tile kb's K and Vt into buffer bb (4 gload_lds per wave)
    auto stageKV = [&](int kb, int bb) {
        const u16* Kg  = K + ((size_t)kv * S_LEN + kb * 64) * HDIM;
        const u16* VTg = V + (size_t)kv * HDIM * S_LEN + kb * 64;
        #pragma unroll
        for (int p = 0; p < 2; p++) {
            int r0  = w * 8 + p * 4;
            int row = r0 + (lane >> 4);
            const u16* src = Kg + (size_t)row * HDIM + (((lane & 15) ^ (row & 7)) << 3);
            __builtin_amdgcn_global_load_lds(
                (const __attribute__((address_space(1))) void*)src,
                (__attribute__((address_space(3))) void*)&Ks[bb][r0 * 128], 16, 0, 0);
        }
        #pragma unroll
        for (int p = 0; p < 2; p++) {
            int r0  = w * 16 + p * 8;
            int row = r0 + (lane >> 3);
            int c   = (lane & 7) ^ (row & 7);
            const u16* src = VTg + (size_t)row * S_LEN + c * 8;
            __builtin_amdgcn_global_load_lds(
                (const __attribute__((address_space(1))) void*)src,
                (__attribute__((address_space(3))) void*)&Vt[bb][r0 * 64], 16, 0, 0);
        }
    };

    // selection predicate (block-uniform: depends on kb, kbMax, h only)
    auto selu_f = [&](int x) {
        return ((kbMax - x) < 17) || (((x + h + 1) & 7) == 0);
    };

    int kb = 0;
    while (!selu_f(kb)) kb++;         // <= 8 steps (vert period 8)
    const int kb0 = kb;
    stageKV(kb0, 0);                   // prologue: 4 outstanding
    int cur = 0;

    while (kb <= kbMax) {
        int kn = kb + 1;
        while (kn <= kbMax && !selu_f(kn)) kn++;   // next selected (<= 8 steps)
        const bool have = (kn <= kbMax);

        stageKV(have ? kn : kb0, cur ^ 1);         // dummy keeps counts uniform
        asm volatile("s_waitcnt vmcnt(4)" ::: "memory");  // forces tile kb's units
        GSBAR();                                          // ... across all waves

        const bool vert = (((kb + h + 1) & 7) == 0);
        const bool mine = (kb <= qbw) && (((qbw - kb) < 16) || vert);
        if (mine) {
            // S = Q K^T  (wave's 16 rows x 64 keys)
            f32x4 sacc[4];
            #pragma unroll
            for (int jj = 0; jj < 4; jj++) { f32x4 z = {0.f,0.f,0.f,0.f}; sacc[jj] = z; }
            __builtin_amdgcn_s_setprio(1);
            #pragma unroll
            for (int ks = 0; ks < 4; ks++) {
                #pragma unroll
                for (int jj = 0; jj < 4; jj++) {
                    bf16x8 bk = *(const bf16x8*)(
                        &Ks[cur][(jj * 16 + ln) * 128 + (((ks * 4 + quad) ^ (ln & 7)) << 3)]);
                    sacc[jj] = __builtin_amdgcn_mfma_f32_16x16x32_bf16(aq[ks], bk, sacc[jj], 0, 0, 0);
                }
            }
            __builtin_amdgcn_s_setprio(0);

            // scale + diagonal mask; per-row max; T13 defer-max
            const bool diag = (kb == qbw);
            float pv[4][4], mxr[4];
            bool grow = false;
            #pragma unroll
            for (int r = 0; r < 4; r++) {
                const int qrow = rb16 + quad * 4 + r;
                float mx = -1e30f;
                #pragma unroll
                for (int jj = 0; jj < 4; jj++) {
                    float s = sacc[jj][r] * ATT_SCALE;
                    if (diag && (jj * 16 + ln) > qrow) s = -1e30f;
                    pv[r][jj] = s;
                    mx = fmaxf(mx, s);
                }
                #pragma unroll
                for (int off = 1; off < 16; off <<= 1)
                    mx = fmaxf(mx, __shfl_xor(mx, off, 64));
                mxr[r] = mx;
                grow |= (mx > mrow[r] + 8.0f);
            }
            if (__any(grow)) {           // wave-uniform rescale path
                #pragma unroll
                for (int r = 0; r < 4; r++) {
                    float mnew  = fmaxf(mrow[r], mxr[r]);
                    float alpha = __expf(mrow[r] - mnew);
                    lrow[r] *= alpha;
                    mrow[r]  = mnew;
                    #pragma unroll
                    for (int n = 0; n < 8; n++) oacc[n][r] *= alpha;
                }
            }
            #pragma unroll
            for (int r = 0; r < 4; r++) {
                float sum = 0.f;
                #pragma unroll
                for (int jj = 0; jj < 4; jj++) {
                    float pe = __expf(pv[r][jj] - mrow[r]);
                    pv[r][jj] = pe;
                    sum += pe;
                }
                #pragma unroll
                for (int off = 1; off < 16; off <<= 1)
                    sum += __shfl_xor(sum, off, 64);
                lrow[r] += sum;
                const int prow = quad * 4 + r;
                #pragma unroll
                for (int jj = 0; jj < 4; jj++)
                    Ps[w][prow * 64 + (((jj * 2 + (ln >> 3)) ^ (prow & 7)) << 3) + (ln & 7)]
                        = f2bf(pv[r][jj]);
            }
            // no barrier: Ps[w] written and read only by wave w (in-order DS pipe)

            // O += P V
            __builtin_amdgcn_s_setprio(1);
            #pragma unroll
            for (int kk = 0; kk < 2; kk++) {
                bf16x8 ap = *(const bf16x8*)(
                    &Ps[w][ln * 64 + (((kk * 4 + quad) ^ (ln & 7)) << 3)]);
                #pragma unroll
                for (int n = 0; n < 8; n++) {
                    bf16x8 bv = *(const bf16x8*)(
                        &Vt[cur][(n * 16 + ln) * 64 + (((kk * 4 + quad) ^ (ln & 7)) << 3)]);
                    oacc[n] = __builtin_amdgcn_mfma_f32_16x16x32_bf16(ap, bv, oacc[n], 0, 0, 0);
                }
            }
            __builtin_amdgcn_s_setprio(0);
        }

        asm volatile("s_waitcnt lgkmcnt(0)" ::: "memory");  // all reads of buf done
        GSBAR();                                            // before next iter DMAs into buf
        cur ^= 1;
        kb = have ? kn : kbMax + 1;
    }

    // CRITICAL drain: final dummy stage still in flight; LDS-DMA landing after
    // s_endpgm corrupts the next workgroup's LDS.
    asm volatile("s_waitcnt vmcnt(0)" ::: "memory");

    #pragma unroll
    for (int n = 0; n < 8; n++) {
        #pragma unroll
        for (int r = 0; r < 4; r++) {
            int pos = qbw * 64 + rb16 + quad * 4 + r;
            float o = oacc[n][r] / lrow[r];
            O[(size_t)pos * (NHEADS * HDIM) + h * HDIM + n * 16 + ln] = f2bf(o);
        }
    }
}

// ---------------- launch ----------------
extern "C" void kernel_launch(void* const* d_in, const int* in_sizes, int n_in,
                              void* d_out, int out_size, void* d_ws, size_t ws_size,
                              hipStream_t stream) {
    const int*   positions = (const int*)d_in[0];
    const float* hidden    = (const float*)d_in[1];
    const float* w_qkv     = (const float*)d_in[2];
    const float* b_qkv     = (const float*)d_in[3];
    const float* w_dense   = (const float*)d_in[4];
    const float* b_dense   = (const float*)d_in[5];
    float* out = (float*)d_out;

    char* ws = (char*)d_ws;
    u16* ws_h    = (u16*)(ws);                    // 2048*4096*2   = 16,777,216
    u16* ws_wqkv = (u16*)(ws + 16777216);         // 6144*4096*2  = 50,331,648
    u16* ws_wd   = (u16*)(ws + 67108864);         // 4096*4096*2  = 33,554,432
    u16* ws_qkv  = (u16*)(ws + 100663296);        // 2048*6144*2  = 25,165,824 (bf16)
    u16* ws_q    = (u16*)(ws + 125829120);        // 32*2048*128*2= 16,777,216
    u16* ws_k    = (u16*)(ws + 142606336);        // 8*2048*128*2 =  4,194,304
    u16* ws_v    = (u16*)(ws + 146800640);        // VT (NKV,HD,S) =  4,194,304
    u16* ws_attn = (u16*)(ws + 150994944);        // 2048*4096*2  = 16,777,216

    cvt_bf16_kernel<<<1024, 256, 0, stream>>>(hidden,  ws_h,    (S_LEN * HID) / 4);
    cvt_bf16_kernel<<<2048, 256, 0, stream>>>(w_qkv,   ws_wqkv, (NQKV * HID) / 4);
    cvt_bf16_kernel<<<2048, 256, 0, stream>>>(w_dense, ws_wd,   (HID * HID) / 4);

    // QKV GEMM: 128x384 tile -> grid 16x16 = 256 blocks (full CU coverage)
    gemm_fc_kernel<384, 3, true><<<dim3(NQKV / 384, S_LEN / 128), 512, 0, stream>>>(
        ws_h, ws_wqkv, b_qkv, ws_qkv, S_LEN, NQKV, HID);

    rope_split_kernel<<<dim3(S_LEN, NHEADS + NKVH), 128, 0, stream>>>(
        ws_qkv, positions, ws_q, ws_k);

    vtrans_kernel<<<dim3(S_LEN / 64, NKVH), 256, 0, stream>>>(ws_qkv, ws_v);

    // attention: QBLK=128, K/V dbuf -> grid (16, 32) = 512 blocks = 2/CU exactly
    attn_bs_kernel<<<dim3(S_LEN / 128, NHEADS), 512, 0, stream>>>(ws_q, ws_k, ws_v, ws_attn);

    // dense GEMM: 128x256 tile -> grid 16x16 = 256 blocks (full CU coverage)
    gemm_fc_kernel<256, 2, false><<<dim3(HID / 256, S_LEN / 128), 512, 0, stream>>>(
        ws_attn, ws_wd, b_dense, out, S_LEN, HID, HID);
}

// Round 13
// 489.719 us; speedup vs baseline: 1.0128x; 1.0128x over previous
//
#include <hip/hip_runtime.h>

#define S_LEN   2048
#define HID     4096
#define NHEADS  32
#define NKVH    8
#define HDIM    128
#define NQKV    6144          // NKV*(QPK+2)*HD = 8*6*128
#define ATT_SCALE (1.0f/128.0f)

typedef unsigned short u16;
typedef __attribute__((ext_vector_type(8))) __bf16 bf16x8;
typedef __attribute__((ext_vector_type(4))) float  f32x4;

__device__ __forceinline__ u16 f2bf(float f) {
    union { float f; unsigned u; } x; x.f = f;
    unsigned u = x.u;
    u += 0x7fffu + ((u >> 16) & 1u);   // round-to-nearest-even
    return (u16)(u >> 16);
}
__device__ __forceinline__ float bf2f(u16 v) {
    union { unsigned u; float f; } x; x.u = ((unsigned)v) << 16; return x.f;
}

// ---------------- fp32 -> bf16 conversion ----------------
__global__ __launch_bounds__(256) void cvt_bf16_kernel(const float* __restrict__ in,
                                                       u16* __restrict__ out, int n4) {
    int stride = gridDim.x * blockDim.x;
    for (int i = blockIdx.x * blockDim.x + threadIdx.x; i < n4; i += stride) {
        float4 v = *(const float4*)(in + (size_t)i * 4);
        ushort4 o = make_ushort4(f2bf(v.x), f2bf(v.y), f2bf(v.z), f2bf(v.w));
        *(ushort4*)(out + (size_t)i * 4) = o;
    }
}

// ---------------- full-coverage GEMM: 128 x BN tile, two-gate interleaved schedule ----------------
// EXACT round-8 schedule (best measured: QKV 101-103 us, MfmaUtil ~44).
//   entering tile t: 2+2LB outstanding {A(t),B0(t),B1(t)}
//   P0: +A(t+1); vmcnt(2+LB) forces A(t)+B0(t); barrier; READ_A; MFMA_B(0).
//   P1: +B0(t+1); vmcnt(2+LB) forces B1(t); barrier; MFMA_B(1); +B1(t+1).
//   end: lgkmcnt(0); barrier.
// Never vmcnt(0) in-loop (T4); drain vmcnt(0) after loop (in-flight LDS-DMA
// at s_endpgm corrupts the next WG's LDS — round-2 root cause).
// B-fragments streamed per-n (round-7: in-loop spill corrupts the vmcnt FIFO).
// T2 swizzle (verified 0 conflicts): phys 16B chunk = logical^(row&7),
// both-sides involution: linear gload_lds dest + pre-swizzled source + XOR read.
#define GFENCE() asm volatile("" ::: "memory")
#define GSBAR()  do { GFENCE(); __builtin_amdgcn_s_barrier(); GFENCE(); } while (0)

template <int BN_, int NB_, bool OUT_BF16>
__global__ __launch_bounds__(512, 2) void gemm_fc_kernel(
    const u16* __restrict__ A,   // M x K  bf16
    const u16* __restrict__ B,   // N x K  bf16
    const float* __restrict__ bias,
    void* __restrict__ Cout,     // M x N
    int M, int N, int K)
{
    constexpr int LB = BN_ / 128;          // gload_lds per B-half per wave
    constexpr int VM = 2 + LB;             // counted-wait value (QKV: 5, dense: 4)
    __shared__ u16 lds[16384 + 2 * BN_ * 64];

    const int tid  = threadIdx.x;
    const int wid  = tid >> 6;        // 0..7
    const int lane = tid & 63;
    const int ln   = lane & 15;
    const int quad = lane >> 4;
    const int wr   = wid >> 2;        // 0..1 (M split)
    const int wc   = wid & 3;         // 0..3 (N split)
    const int tileM = blockIdx.y * 128;
    const int tileN = blockIdx.x * BN_;

    f32x4 acc[2][NB_][4];             // [b][n][m]
    #pragma unroll
    for (int b = 0; b < 2; b++)
        #pragma unroll
        for (int n = 0; n < NB_; n++)
            #pragma unroll
            for (int m = 0; m < 4; m++) {
                f32x4 z = {0.f, 0.f, 0.f, 0.f};
                acc[b][n][m] = z;
            }

    const int srho = lane >> 3;                       // row within 8-row group
    const int scol = (((lane & 7) ^ srho) << 3);      // pre-swizzled source chunk

    auto gload = [&](const u16* src, u16* dst) {
        __builtin_amdgcn_global_load_lds(
            (const __attribute__((address_space(1))) void*)src,
            (__attribute__((address_space(3))) void*)dst, 16, 0, 0);
    };
    // A unit: 128 rows, 2 loads/wave
    auto stage_A = [&](int kk, int bb) {
        const int base = bb * 8192;
        #pragma unroll
        for (int s = 0; s < 2; s++) {
            const int rho0 = s * 64 + wid * 8;        // wave-uniform, ≡0 mod 8
            const int rho  = rho0 + srho;
            const u16* src = A + (size_t)(tileM + rho) * K + (size_t)kk * 64 + scol;
            gload(src, &lds[base + rho0 * 64]);
        }
    };
    // B half h: BN/2 rows, LB loads/wave
    auto stage_Bh = [&](int h, int kk, int bb) {
        const int base = 16384 + bb * (BN_ * 64) + h * ((BN_ / 2) * 64);
        #pragma unroll
        for (int s = 0; s < LB; s++) {
            const int rho0 = s * 64 + wid * 8;
            const int rho  = rho0 + srho;
            const u16* src = B + (size_t)(tileN + h * (BN_ / 2) + rho) * K
                               + (size_t)kk * 64 + scol;
            gload(src, &lds[base + rho0 * 64]);
        }
    };

#define WAIT_VM()                                                                   \
    do {                                                                            \
        if constexpr (VM == 5) asm volatile("s_waitcnt vmcnt(5)" ::: "memory");     \
        else                   asm volatile("s_waitcnt vmcnt(4)" ::: "memory");     \
    } while (0)

#define READ_A()                                                                    \
    do {                                                                            \
        _Pragma("unroll")                                                           \
        for (int m = 0; m < 4; m++) {                                               \
            const int ra = wr * 64 + m * 16 + ln;                                   \
            const int ab = buf * 8192 + ra * 64;                                    \
            const int rx = ra & 7;                                                  \
            af[m][0] = *(const bf16x8*)(&lds[ab + ((quad ^ rx) << 3)]);             \
            af[m][1] = *(const bf16x8*)(&lds[ab + (((4 + quad) ^ rx) << 3)]);       \
        }                                                                           \
    } while (0)

// streamed: one bfr pair live at a time (no in-loop spill risk)
#define MFMA_B(b_)                                                                  \
    do {                                                                            \
        __builtin_amdgcn_s_setprio(1);                                              \
        _Pragma("unroll")                                                           \
        for (int n = 0; n < NB_; n++) {                                             \
            const int rb = (b_) * (BN_ / 2) + wc * (NB_ * 16) + n * 16 + ln;        \
            const int bb = 16384 + buf * (BN_ * 64) + rb * 64;                      \
            const int rx = rb & 7;                                                  \
            bf16x8 b0 = *(const bf16x8*)(&lds[bb + ((quad ^ rx) << 3)]);            \
            bf16x8 b1 = *(const bf16x8*)(&lds[bb + (((4 + quad) ^ rx) << 3)]);      \
            _Pragma("unroll")                                                       \
            for (int m = 0; m < 4; m++) {                                           \
                acc[b_][n][m] = __builtin_amdgcn_mfma_f32_16x16x32_bf16(            \
                    af[m][0], b0, acc[b_][n][m], 0, 0, 0);                          \
                acc[b_][n][m] = __builtin_amdgcn_mfma_f32_16x16x32_bf16(            \
                    af[m][1], b1, acc[b_][n][m], 0, 0, 0);                          \
            }                                                                       \
        }                                                                           \
        __builtin_amdgcn_s_setprio(0);                                              \
    } while (0)

    const int nIter = K / 64;

    // prologue: tile 0 -> buf0, order A, B0, B1 (order matters for the ledger)
    stage_A(0, 0); stage_Bh(0, 0, 0); stage_Bh(1, 0, 0);

    bf16x8 af[4][2];

    for (int t = 0; t < nIter; t++) {
        const int buf = t & 1;
        const int bn  = buf ^ 1;
        const int kn  = (t + 1 == nIter) ? 0 : t + 1;   // final-iter dummy keeps counts uniform

        // ---- P0: b=0 needs A(t) + B0(t) ----
        stage_A(kn, bn);
        WAIT_VM();             // forces A(t), B0(t) (this wave)
        GSBAR();               // ... across all waves
        READ_A();
        MFMA_B(0);

        // ---- P1: b=1 needs B1(t); af reused ----
        stage_Bh(0, kn, bn);
        WAIT_VM();             // forces exactly B1(t)
        GSBAR();
        MFMA_B(1);
        stage_Bh(1, kn, bn);

        asm volatile("s_waitcnt lgkmcnt(0)" ::: "memory");  // all buf reads complete
        GSBAR();                                            // before t+1 DMAs into buf
    }

    // CRITICAL drain: final-iter dummy stages still in flight; LDS-DMA landing
    // after s_endpgm faults / corrupts the next workgroup's LDS.
    asm volatile("s_waitcnt vmcnt(0)" ::: "memory");

#undef WAIT_VM
#undef READ_A
#undef MFMA_B

    // epilogue
    #pragma unroll
    for (int b = 0; b < 2; b++)
        #pragma unroll
        for (int n = 0; n < NB_; n++) {
            const int col = tileN + b * (BN_ / 2) + wc * (NB_ * 16) + n * 16 + ln;
            const float bv = bias[col];
            #pragma unroll
            for (int m = 0; m < 4; m++) {
                #pragma unroll
                for (int r = 0; r < 4; r++) {
                    const int row = tileM + wr * 64 + m * 16 + quad * 4 + r;
                    float v = acc[b][n][m][r] + bv;
                    if (OUT_BF16)
                        ((u16*)Cout)[(size_t)row * N + col] = f2bf(v);
                    else
                        ((float*)Cout)[(size_t)row * N + col] = v;
                }
            }
        }
}

// ---------------- RoPE cos/sin table: cs[pos][d2] (fp32) ----------------
// Round-13: the old rope kernel computed expf+sincosf in 10.5M threads for
// only 2048x64 = 131K unique (pos,d2) pairs — 80x redundant transcendentals.
// Precompute once (this kernel, ~2 us); rope becomes pure memory-bound.
__global__ __launch_bounds__(256) void rope_cs_kernel(
    const int* __restrict__ positions, float2* __restrict__ cs)
{
    int i = blockIdx.x * 256 + threadIdx.x;      // 0 .. S*64-1
    if (i >= S_LEN * 64) return;
    int pos = i >> 6, d2 = i & 63;
    float p = (float)positions[pos];
    float inv = expf(-(float)d2 * (13.815510557964274f / 64.0f)); // 1e6^(-d2/64)
    float s, c;
    sincosf(p * inv, &s, &c);
    cs[i] = make_float2(c, s);
}

// ---------------- RoPE + split qkv (bf16 in, bf16 out), vectorized ----------------
// grid (S, 5), block 64: hy = by*8 + (t>>3) (0..39 = 32 q-heads + 8 k-heads),
// d2_0 = (t&7)*8. Each thread: 2 x 16B loads (both rotation halves),
// 8 float2 table reads, 2 x 16B stores. v is handled by vtrans_kernel.
__global__ __launch_bounds__(64) void rope_split_kernel(
    const u16* __restrict__ qkv, const float2* __restrict__ cs,
    u16* __restrict__ qb_o, u16* __restrict__ kb_o)
{
    const int pos  = blockIdx.x;
    const int t    = threadIdx.x;
    const int hy   = blockIdx.y * 8 + (t >> 3);
    const int d2_0 = (t & 7) * 8;

    const u16* src;
    u16* dst;
    if (hy < NHEADS) {                        // q head
        int kv = hy >> 2, qi = hy & 3;
        src = qkv + (size_t)pos * NQKV + (kv * 6 + qi) * HDIM;
        dst = qb_o + ((size_t)hy * S_LEN + pos) * HDIM;
    } else {                                  // k head
        int kv = hy - NHEADS;
        src = qkv + (size_t)pos * NQKV + (kv * 6 + 4) * HDIM;
        dst = kb_o + ((size_t)kv * S_LEN + pos) * HDIM;
    }

    uint4 v1 = *(const uint4*)(src + d2_0);        // x1[d2_0 .. +7]
    uint4 v2 = *(const uint4*)(src + d2_0 + 64);   // x2[d2_0 .. +7]
    const u16* p1 = (const u16*)&v1;
    const u16* p2 = (const u16*)&v2;
    const float2* csr = cs + pos * 64 + d2_0;

    u16 o1[8], o2[8];
    #pragma unroll
    for (int j = 0; j < 8; j++) {
        float c = csr[j].x, s = csr[j].y;
        float x1 = bf2f(p1[j]), x2 = bf2f(p2[j]);
        o1[j] = f2bf(x1 * c - x2 * s);
        o2[j] = f2bf(x2 * c + x1 * s);
    }
    *(uint4*)(dst + d2_0)      = *(uint4*)o1;
    *(uint4*)(dst + d2_0 + 64) = *(uint4*)o2;
}

// ---------------- one-shot V transpose: qkv -> VT (NKV, HD, S) ----------------
__global__ __launch_bounds__(256) void vtrans_kernel(
    const u16* __restrict__ qkv,   // (S, NQKV)
    u16* __restrict__ VT)          // (NKV, HDIM, S)
{
    __shared__ u16 T[64][HDIM + 8];
    const int s0 = blockIdx.x * 64;
    const int kv = blockIdx.y;
    const int tid = threadIdx.x;
    // coalesced read: 64 pos x 128 dim
    #pragma unroll
    for (int p = 0; p < 4; p++) {
        int pos = p * 16 + (tid >> 4);
        int d   = (tid & 15) * 8;
        *(uint4*)&T[pos][d] =
            *(const uint4*)(qkv + (size_t)(s0 + pos) * NQKV + (kv * 6 + 5) * HDIM + d);
    }
    __syncthreads();
    // coalesced write: 128 dim rows x 64 pos
    #pragma unroll
    for (int p = 0; p < 4; p++) {
        int d  = p * 32 + (tid >> 3);
        int sc = (tid & 7) * 8;
        u16 tmp[8];
        #pragma unroll
        for (int j = 0; j < 8; j++) tmp[j] = T[sc + j][d];
        *(uint4*)(VT + ((size_t)kv * HDIM + d) * S_LEN + s0 + sc) = *(uint4*)tmp;
    }
}

// ---------------- blocksparse flash attention, QBLK=128 ----------------
// Round-13: reverted to round-11 exact version (best measured; round-12's
// K/V dbuf was neutral-to-negative — stage latency already hidden by TLP).
// 128 q-rows per block (8 waves, 512 thr), grid (S/128, NH) = 512 blocks.
// Waves 0-3 own 64-row block qbw=2*blk, waves 4-7 own 2*blk+1. Stage set =
// union over halves (block-uniform -> continue is barrier-safe); per-wave
// compute guard 'mine' (wave-uniform, barriers outside). LDS 48 KB ->
// 3 blocks/CU. V pre-transposed; 3-bit XOR involution; T13 defer-max;
// reversed dispatch; setprio on MFMA clusters.
__global__ __launch_bounds__(512, 4) void attn_bs_kernel(
    const u16* __restrict__ Q,   // (NH, S, HD) bf16
    const u16* __restrict__ K,   // (NKV, S, HD)
    const u16* __restrict__ V,   // (NKV, HD, S)  TRANSPOSED
    u16* __restrict__ O)         // (S, NH*HD) bf16
{
    __shared__ u16 Ks[64 * 128];      // 16 KB, swizzled
    __shared__ u16 Vt[128 * 64];      // 16 KB, V^T, swizzled
    __shared__ u16 Ps[8][16 * 64];    // 16 KB, per-wave P, swizzled

    const int blk = (int)gridDim.x - 1 - (int)blockIdx.x;  // heavy blocks first
    const int h   = blockIdx.y;
    const int kv  = h >> 2;
    const int tid  = threadIdx.x;
    const int w    = tid >> 6;        // 0..7
    const int lane = tid & 63;
    const int ln   = lane & 15;
    const int quad = lane >> 4;
    const int qbw  = 2 * blk + (w >> 2);   // this wave's 64-row block index
    const int rb16 = (w & 3) * 16;         // wave's row base within its 64-block

    bf16x8 aq[4];
    {
        const u16* Qg = Q + ((size_t)h * S_LEN + qbw * 64 + rb16 + ln) * HDIM + quad * 8;
        #pragma unroll
        for (int ks = 0; ks < 4; ks++)
            aq[ks] = *(const bf16x8*)(Qg + ks * 32);
    }

    f32x4 oacc[8];
    #pragma unroll
    for (int n = 0; n < 8; n++) { f32x4 z = {0.f,0.f,0.f,0.f}; oacc[n] = z; }
    float mrow[4] = {-1e30f, -1e30f, -1e30f, -1e30f};
    float lrow[4] = {0.f, 0.f, 0.f, 0.f};

    const int kbMax = 2 * blk + 1;
    for (int kb = 0; kb <= kbMax; kb++) {
        const bool vert = (((kb + h + 1) & 7) == 0);
        const bool selu = ((kbMax - kb) < 17) || vert;   // block-uniform
        if (!selu) continue;

        __syncthreads();   // previous iteration's LDS reads complete

        const u16* Kg  = K + ((size_t)kv * S_LEN + kb * 64) * HDIM;
        const u16* VTg = V + (size_t)kv * HDIM * S_LEN + kb * 64;

        // K stage: 2 gload_lds/wave (4 rows each); pre-swizzled source
        #pragma unroll
        for (int p = 0; p < 2; p++) {
            int r0  = w * 8 + p * 4;
            int row = r0 + (lane >> 4);
            const u16* src = Kg + (size_t)row * HDIM + (((lane & 15) ^ (row & 7)) << 3);
            __builtin_amdgcn_global_load_lds(
                (const __attribute__((address_space(1))) void*)src,
                (__attribute__((address_space(3))) void*)&Ks[r0 * 128], 16, 0, 0);
        }
        // Vt stage: 2 gload_lds/wave (8 dim-rows each); 16B contiguous along keys
        #pragma unroll
        for (int p = 0; p < 2; p++) {
            int r0  = w * 16 + p * 8;
            int row = r0 + (lane >> 3);
            int c   = (lane & 7) ^ (row & 7);
            const u16* src = VTg + (size_t)row * S_LEN + c * 8;
            __builtin_amdgcn_global_load_lds(
                (const __attribute__((address_space(1))) void*)src,
                (__attribute__((address_space(3))) void*)&Vt[r0 * 64], 16, 0, 0);
        }
        __syncthreads();   // drains vmcnt -> K, Vt resident

        const bool mine = (kb <= qbw) && (((qbw - kb) < 16) || vert);
        if (mine) {
            // S = Q K^T  (wave's 16 rows x 64 keys)
            f32x4 sacc[4];
            #pragma unroll
            for (int jj = 0; jj < 4; jj++) { f32x4 z = {0.f,0.f,0.f,0.f}; sacc[jj] = z; }
            __builtin_amdgcn_s_setprio(1);
            #pragma unroll
            for (int ks = 0; ks < 4; ks++) {
                #pragma unroll
                for (int jj = 0; jj < 4; jj++) {
                    bf16x8 bk = *(const bf16x8*)(
                        &Ks[(jj * 16 + ln) * 128 + (((ks * 4 + quad) ^ (ln & 7)) << 3)]);
                    sacc[jj] = __builtin_amdgcn_mfma_f32_16x16x32_bf16(aq[ks], bk, sacc[jj], 0, 0, 0);
                }
            }
            __builtin_amdgcn_s_setprio(0);

            // scale + diagonal mask; per-row max; T13 defer-max
            const bool diag = (kb == qbw);
            float pv[4][4], mxr[4];
            bool grow = false;
            #pragma unroll
            for (int r = 0; r < 4; r++) {
                const int qrow = rb16 + quad * 4 + r;
                float mx = -1e30f;
                #pragma unroll
                for (int jj = 0; jj < 4; jj++) {
                    float s = sacc[jj][r] * ATT_SCALE;
                    if (diag && (jj * 16 + ln) > qrow) s = -1e30f;
                    pv[r][jj] = s;
                    mx = fmaxf(mx, s);
                }
                #pragma unroll
                for (int off = 1; off < 16; off <<= 1)
                    mx = fmaxf(mx, __shfl_xor(mx, off, 64));
                mxr[r] = mx;
                grow |= (mx > mrow[r] + 8.0f);
            }
            if (__any(grow)) {           // wave-uniform rescale path
                #pragma unroll
                for (int r = 0; r < 4; r++) {
                    float mnew  = fmaxf(mrow[r], mxr[r]);
                    float alpha = __expf(mrow[r] - mnew);
                    lrow[r] *= alpha;
                    mrow[r]  = mnew;
                    #pragma unroll
                    for (int n = 0; n < 8; n++) oacc[n][r] *= alpha;
                }
            }
            #pragma unroll
            for (int r = 0; r < 4; r++) {
                float sum = 0.f;
                #pragma unroll
                for (int jj = 0; jj < 4; jj++) {
                    float pe = __expf(pv[r][jj] - mrow[r]);
                    pv[r][jj] = pe;
                    sum += pe;
                }
                #pragma unroll
                for (int off = 1; off < 16; off <<= 1)
                    sum += __shfl_xor(sum, off, 64);
                lrow[r] += sum;
                const int prow = quad * 4 + r;
                #pragma unroll
                for (int jj = 0; jj < 4; jj++)
                    Ps[w][prow * 64 + (((jj * 2 + (ln >> 3)) ^ (prow & 7)) << 3) + (ln & 7)]
                        = f2bf(pv[r][jj]);
            }
            // no barrier: Ps[w] is written and read only by wave w (in-order DS pipe)

            // O += P V
            __builtin_amdgcn_s_setprio(1);
            #pragma unroll
            for (int kk = 0; kk < 2; kk++) {
                bf16x8 ap = *(const bf16x8*)(
                    &Ps[w][ln * 64 + (((kk * 4 + quad) ^ (ln & 7)) << 3)]);
                #pragma unroll
                for (int n = 0; n < 8; n++) {
                    bf16x8 bv = *(const bf16x8*)(
                        &Vt[(n * 16 + ln) * 64 + (((kk * 4 + quad) ^ (ln & 7)) << 3)]);
                    oacc[n] = __builtin_amdgcn_mfma_f32_16x16x32_bf16(ap, bv, oacc[n], 0, 0, 0);
                }
            }
            __builtin_amdgcn_s_setprio(0);
        }
    }

    #pragma unroll
    for (int n = 0; n < 8; n++) {
        #pragma unroll
        for (int r = 0; r < 4; r++) {
            int pos = qbw * 64 + rb16 + quad * 4 + r;
            float o = oacc[n][r] / lrow[r];
            O[(size_t)pos * (NHEADS * HDIM) + h * HDIM + n * 16 + ln] = f2bf(o);
        }
    }
}

// ---------------- launch ----------------
extern "C" void kernel_launch(void* const* d_in, const int* in_sizes, int n_in,
                              void* d_out, int out_size, void* d_ws, size_t ws_size,
                              hipStream_t stream) {
    const int*   positions = (const int*)d_in[0];
    const float* hidden    = (const float*)d_in[1];
    const float* w_qkv     = (const float*)d_in[2];
    const float* b_qkv     = (const float*)d_in[3];
    const float* w_dense   = (const float*)d_in[4];
    const float* b_dense   = (const float*)d_in[5];
    float* out = (float*)d_out;

    char* ws = (char*)d_ws;
    u16* ws_h    = (u16*)(ws);                    // 2048*4096*2   = 16,777,216
    u16* ws_wqkv = (u16*)(ws + 16777216);         // 6144*4096*2  = 50,331,648
    u16* ws_wd   = (u16*)(ws + 67108864);         // 4096*4096*2  = 33,554,432
    u16* ws_qkv  = (u16*)(ws + 100663296);        // 2048*6144*2  = 25,165,824 (bf16)
    u16* ws_q    = (u16*)(ws + 125829120);        // 32*2048*128*2= 16,777,216
    u16* ws_k    = (u16*)(ws + 142606336);        // 8*2048*128*2 =  4,194,304
    u16* ws_v    = (u16*)(ws + 146800640);        // VT (NKV,HD,S) =  4,194,304
    u16* ws_attn = (u16*)(ws + 150994944);        // 2048*4096*2  = 16,777,216
    // RoPE cos/sin table ALIASES the first 1 MB of ws_attn: written by
    // rope_cs_kernel, consumed by rope_split_kernel, dead before attn
    // overwrites ws_attn (stream-ordered) — no workspace growth.
    float2* ws_cs = (float2*)(ws + 150994944);    // 2048*64*8 = 1,048,576

    cvt_bf16_kernel<<<1024, 256, 0, stream>>>(hidden,  ws_h,    (S_LEN * HID) / 4);
    cvt_bf16_kernel<<<2048, 256, 0, stream>>>(w_qkv,   ws_wqkv, (NQKV * HID) / 4);
    cvt_bf16_kernel<<<2048, 256, 0, stream>>>(w_dense, ws_wd,   (HID * HID) / 4);

    // QKV GEMM: 128x384 tile -> grid 16x16 = 256 blocks (full CU coverage)
    gemm_fc_kernel<384, 3, true><<<dim3(NQKV / 384, S_LEN / 128), 512, 0, stream>>>(
        ws_h, ws_wqkv, b_qkv, ws_qkv, S_LEN, NQKV, HID);

    rope_cs_kernel<<<(S_LEN * 64) / 256, 256, 0, stream>>>(positions, ws_cs);
    rope_split_kernel<<<dim3(S_LEN, 5), 64, 0, stream>>>(ws_qkv, ws_cs, ws_q, ws_k);

    vtrans_kernel<<<dim3(S_LEN / 64, NKVH), 256, 0, stream>>>(ws_qkv, ws_v);

    // attention: QBLK=128 -> grid (16, 32) = 512 blocks, 512 threads
    attn_bs_kernel<<<dim3(S_LEN / 128, NHEADS), 512, 0, stream>>>(ws_q, ws_k, ws_v, ws_attn);

    // dense GEMM: 128x256 tile -> grid 16x16 = 256 blocks (full CU coverage)
    gemm_fc_kernel<256, 2, false><<<dim3(HID / 256, S_LEN / 128), 512, 0, stream>>>(
        ws_attn, ws_wd, b_dense, out, S_LEN, HID, HID);
}